// Round 1
// 187.204 us; speedup vs baseline: 1.0261x; 1.0261x over previous
//
#include <hip/hip_runtime.h>

#define NB 128
#define NM 1024
#define NK 32
#define NS 16                   // per-half survivor slots (avg ~15; truncation tolerated)
#define CUT2 25.0f
#define CUT2_BITS 0x41C80000u   // bit pattern of 25.0f
#define KEYMASK   0xFFFFFC00u   // top 22 bits d2, low 10 bits index

typedef unsigned int   u32;
typedef unsigned short u16;
typedef float vf4 __attribute__((ext_vector_type(4)));

// Prepass: scanb = {-2x,-2y,-2z,|p|^2}. Single buffer: raw coords are exactly
// recoverable as x = -0.5f * (-2x) (power-of-two scale, bit-exact).
__global__ __launch_bounds__(256) void pack_atoms(const float* __restrict__ pos,
                                                  float4* __restrict__ scanb)
{
  int i = blockIdx.x * 256 + threadIdx.x;
  float x = pos[3*i+0], y = pos[3*i+1], z = pos[3*i+2];
  float sq = x*x + y*y + z*z;
  scanb[i] = make_float4(-2.f*x, -2.f*y, -2.f*z, sq);
}

__device__ __forceinline__ void ce_asc(u32 &a, u32 &b) {
  u32 mn = a < b ? a : b;
  u32 mx = a < b ? b : a;
  a = mn; b = mx;
}

template <int N, int K, int D>
__device__ __forceinline__ void bitonic_pass(u32* r) {
#pragma unroll
  for (int i = 0; i < N; ++i)
    if ((i & D) == 0) {
      if ((i & K) == 0) ce_asc(r[i], r[i | D]);
      else              ce_asc(r[i | D], r[i]);
    }
}

// 2 threads per center (tid&127 = center lane, tid>>7 = candidate half).
// Scan: double-buffered 8-deep prefetch of broadcast float4 loads.
// R6 fix: sched_barrier(0) pins each prefetch group ahead of the compute body
// (R5 shipped with VGPR_Count=44 — the compiler had sunk the loads, collapsing
// the pipeline to <1 body of latency cover; VALUBusy was stuck at 41%).
// LDS: single float4 scan-form array -> phase-2/4 gathers are one ds_read_b128
// instead of 4 conflicted ds_read_b32 (SQ_LDS_BANK_CONFLICT was 10% of cycles).
__global__ __launch_bounds__(256, 4) void radius_knn(const float4* __restrict__ scanb,
                                                     float* __restrict__ out)
{
  __shared__ float4 s4[NM];                            // 16 KB scan-form {-2x,-2y,-2z,sq}
  __shared__ u32 lmem[4096];                           // 16 KB: lists then publish buf
  u16* lists = (u16*)lmem;                             // [NS][256] u16 = 8 KB

  const int tid  = threadIdx.x;
  const int lane = tid & 127;
  const int half = tid >> 7;
  const int molb = blockIdx.x & 127;        // molecule (XCD-local grouping)
  const int q8   = blockIdx.x >> 7;
  const int c    = molb * NM + q8 * 128 + lane;
  const int mloc = c & (NM - 1);

  const float4* st = scanb + (size_t)molb * NM;
  for (int t = tid; t < NM; t += 256) s4[t] = st[t];
  __syncthreads();

  const float4 mc = s4[mloc];
  const float mex = -0.5f * mc.x, mey = -0.5f * mc.y, mez = -0.5f * mc.z;
  const float mew = mc.w;

  // ---- phase 1: scan 512 candidates, 8-deep double-buffered prefetch ----
  // base derived from thread-varying c -> vector broadcast loads (NOT s_load;
  // R4 proved scalarization serializes on lgkmcnt with the lists ds_writes)
  const float4* mp = scanb + ((size_t)(c >> 10) << 10);
  const int jbase = half * 512;
  int cnt = 0;
  float4 ta[8], tb[8];
#pragma unroll
  for (int u = 0; u < 8; ++u) ta[u] = mp[jbase + u];
  __builtin_amdgcn_sched_barrier(0);        // pin prologue loads

  auto body = [&](const float4* t, int j0) {
#pragma unroll
    for (int u = 0; u < 8; ++u) {
      float d2 = __builtin_fmaf(mex, t[u].x,
                 __builtin_fmaf(mey, t[u].y,
                 __builtin_fmaf(mez, t[u].z, mew + t[u].w)));
      int slot = cnt < NS ? cnt : (NS - 1);
      lists[slot * 256 + tid] = (u16)(j0 + u);
      cnt += (d2 <= CUT2) ? 1 : 0;
    }
  };

  for (int g = 0; g < 64; g += 2) {
    const int j1 = jbase + (((g + 1) & 63) << 3);
#pragma unroll
    for (int u = 0; u < 8; ++u) tb[u] = mp[j1 + u];   // prefetch g+1
    __builtin_amdgcn_sched_barrier(0);                 // don't sink tb loads
    body(ta, jbase + (g << 3));                        // process g
    const int j2 = jbase + (((g + 2) & 63) << 3);
#pragma unroll
    for (int u = 0; u < 8; ++u) ta[u] = mp[j2 + u];   // prefetch g+2 (wraps)
    __builtin_amdgcn_sched_barrier(0);                 // don't sink ta loads
    body(tb, jbase + ((g + 1) << 3));                  // process g+1
  }
  if (cnt > NS) cnt = NS;

  // ---- phase 2: keys + bitonic sort 16 ----
  const u32 PADK = 0x7F800000u | (u32)mloc;   // +inf self-pad, sorts last
  u32 r[NK];
#pragma unroll
  for (int k = 0; k < NS; ++k) {
    u32 key = PADK;
    if (k < cnt) {
      int j = lists[k * 256 + tid];
      float4 cj = s4[j];                       // one ds_read_b128 gather
      float d2 = fmaxf(__builtin_fmaf(mex, cj.x,
                  __builtin_fmaf(mey, cj.y,
                  __builtin_fmaf(mez, cj.z, mew + cj.w))), 0.f);
      key = (__float_as_uint(d2) & KEYMASK) | (u32)j;
    }
    r[k] = key;
  }
  bitonic_pass<16, 2, 1>(r);
  bitonic_pass<16, 4, 2>(r); bitonic_pass<16, 4, 1>(r);
  bitonic_pass<16, 8, 4>(r); bitonic_pass<16, 8, 2>(r); bitonic_pass<16, 8, 1>(r);
  bitonic_pass<16,16, 8>(r); bitonic_pass<16,16, 4>(r); bitonic_pass<16,16, 2>(r); bitonic_pass<16,16, 1>(r);

  // ---- phase 3: symmetric merge (both halves publish, both merge) ----
  __syncthreads();                       // lists dead; alias lmem as publish buf
  {
    u32* myp = lmem + half * 2048 + lane * 16;
#pragma unroll
    for (int k = 0; k < NS; ++k) myp[(k + lane) & 15] = r[k];   // bank-swizzled
  }
  __syncthreads();
  {
    u32* op = lmem + (1 - half) * 2048 + lane * 16;
#pragma unroll
    for (int i = 0; i < NS; ++i) r[16 + i] = op[((15 - i) + lane) & 15]; // desc
  }
  // asc16 ++ desc16 = bitonic -> 5 merge passes give sorted 32
  bitonic_pass<32,32,16>(r); bitonic_pass<32,32, 8>(r); bitonic_pass<32,32, 4>(r);
  bitonic_pass<32,32, 2>(r); bitonic_pass<32,32, 1>(r);

  // ---- phase 4: split emit. half0: src/dst/w; half1: vec ----
  const long long E = (long long)NB * NM * NK;
  const float base = (float)((c >> 10) * NM);
  const float nmex = -mex, nmey = -mey, nmez = -mez;

  if (!half) {
    vf4* ps = (vf4*)(out       + (size_t)c * NK);
    vf4* pd = (vf4*)(out +   E + (size_t)c * NK);
    vf4* pw = (vf4*)(out + 2*E + (size_t)c * NK);
    const float fc = (float)c;
    const vf4 dstv = {fc, fc, fc, fc};
#pragma unroll
    for (int q = 0; q < 8; ++q) {
      float sv[4], wv[4];
#pragma unroll
      for (int u = 0; u < 4; ++u) {
        u32 key = r[4*q + u];
        int idx = (int)(key & 1023u);
        float4 cj = s4[idx];                           // one b128 gather
        bool valid = (key & KEYMASK) <= CUT2_BITS;     // pads (+inf) fail
        float vx = __builtin_fmaf(-0.5f, cj.x, nmex);  // exact: x - mex
        float vy = __builtin_fmaf(-0.5f, cj.y, nmey);
        float vz = __builtin_fmaf(-0.5f, cj.z, nmez);
        bool wm  = valid && (idx != mloc);
        float d2s = vx*vx + vy*vy + vz*vz;
        wv[u] = wm ? sqrtf(d2s) : 0.0f;
        sv[u] = base + (float)idx;
      }
      ps[q] = (vf4){sv[0], sv[1], sv[2], sv[3]};
      pd[q] = dstv;
      pw[q] = (vf4){wv[0], wv[1], wv[2], wv[3]};
    }
  } else {
    vf4* pv = (vf4*)(out + 3*E + (size_t)c * NK * 3);
#pragma unroll
    for (int q = 0; q < 8; ++q) {
      float vv[12];
#pragma unroll
      for (int u = 0; u < 4; ++u) {
        int idx = (int)(r[4*q + u] & 1023u);
        float4 cj = s4[idx];                           // one b128 gather
        vv[3*u+0] = __builtin_fmaf(-0.5f, cj.x, nmex);
        vv[3*u+1] = __builtin_fmaf(-0.5f, cj.y, nmey);
        vv[3*u+2] = __builtin_fmaf(-0.5f, cj.z, nmez);
      }
      pv[3*q+0] = (vf4){vv[0], vv[1], vv[2],  vv[3]};
      pv[3*q+1] = (vf4){vv[4], vv[5], vv[6],  vv[7]};
      pv[3*q+2] = (vf4){vv[8], vv[9], vv[10], vv[11]};
    }
  }
}

extern "C" void kernel_launch(void* const* d_in, const int* in_sizes, int n_in,
                              void* d_out, int out_size, void* d_ws, size_t ws_size,
                              hipStream_t stream) {
  const float* pos = (const float*)d_in[0];
  float* out = (float*)d_out;
  float4* scanb = (float4*)d_ws;                       // 2 MB (ws was >=4 MB in prior runs)
  hipLaunchKernelGGL(pack_atoms, dim3((NB*NM)/256), dim3(256), 0, stream, pos, scanb);
  hipLaunchKernelGGL(radius_knn, dim3(2*(NB*NM)/256), dim3(256), 0, stream, scanb, out);
}

// Round 3
// 186.986 us; speedup vs baseline: 1.0273x; 1.0012x over previous
//
#include <hip/hip_runtime.h>

#define NB 128
#define NM 1024
#define NK 32
#define NQ 4                    // candidate quarters (one wave each)
#define NS 12                   // per-quarter survivor slots (avg ~7.6; P(>12)~4%)
#define CUT2 25.0f
#define CUT2_BITS 0x41C80000u   // bit pattern of 25.0f
#define KEYMASK   0xFFFFFC00u   // top 22 bits d2, low 10 bits index

typedef unsigned int   u32;
typedef unsigned short u16;
typedef float vf4 __attribute__((ext_vector_type(4)));

// Prepass: scanb = {-2x,-2y,-2z,|p|^2}. Raw coords recovered exactly as
// x = -0.5f * (-2x) (power-of-two scale, bit-exact).
__global__ __launch_bounds__(256) void pack_atoms(const float* __restrict__ pos,
                                                  float4* __restrict__ scanb)
{
  int i = blockIdx.x * 256 + threadIdx.x;
  float x = pos[3*i+0], y = pos[3*i+1], z = pos[3*i+2];
  float sq = x*x + y*y + z*z;
  scanb[i] = make_float4(-2.f*x, -2.f*y, -2.f*z, sq);
}

__device__ __forceinline__ void ce_asc(u32 &a, u32 &b) {
  u32 mn = a < b ? a : b;
  u32 mx = a < b ? b : a;
  a = mn; b = mx;
}

template <int N, int K, int D>
__device__ __forceinline__ void bitonic_pass(u32* r) {
#pragma unroll
  for (int i = 0; i < N; ++i)
    if ((i & D) == 0) {
      if ((i & K) == 0) ce_asc(r[i], r[i | D]);
      else              ce_asc(r[i | D], r[i]);
    }
}

// R8: fixes R7's launch bug — grid expression evaluated to 1024 blocks, so
// centers 512..1023 of every molecule were never written (absmax=131072 = zeros
// where ref has molecule-127 indices). Grid is now NB*(NM/64)=2048 explicitly.
// Also: launch_bounds (256,5) (LDS caps at 5 blocks/CU anyway; (256,8) only
// forced spills), and emit uses static r[] indices (runtime k0 would send r to
// scratch, rule #20).
// Shape: 64 centers x 4 quarter-scans per block (wave-uniform quarter), NS=12
// slots/quarter, symmetric pair merge (16 keys) then cross-pair min-fold (32).
__global__ __launch_bounds__(256, 5) void radius_knn(const float4* __restrict__ scanb,
                                                     float* __restrict__ out)
{
  __shared__ float4 s4[NM];     // 16 KB scan-form {-2x,-2y,-2z,sq}
  __shared__ u32 lmem[4096];    // 16 KB: survivor lists, then publish buffer
  u16* lists = (u16*)lmem;      // [NS][256] u16 = 6 KB

  const int tid     = threadIdx.x;
  const int ctr     = tid & 63;          // center within block
  const int quarter = tid >> 6;          // wave index = candidate quarter
  const int molb    = blockIdx.x & 127;  // same-XCD blocks share molecule
  const int grp     = blockIdx.x >> 7;   // center group [0,16)
  const int c       = molb * NM + grp * 64 + ctr;
  const int mloc    = c & (NM - 1);

  const float4* st = scanb + (size_t)molb * NM;
  for (int t = tid; t < NM; t += 256) s4[t] = st[t];
  __syncthreads();

  const float4 mc = s4[mloc];
  const float mex = -0.5f * mc.x, mey = -0.5f * mc.y, mez = -0.5f * mc.z;
  const float mew = mc.w;

  // ---- phase 1: scan this quarter's 256 candidates (broadcast loads) ----
  const float4* mp = scanb + ((size_t)(c >> 10) << 10);
  const int jbase = quarter * 256;
  int cnt = 0;
  float4 ta[4], tb[4];
#pragma unroll
  for (int u = 0; u < 4; ++u) ta[u] = mp[jbase + u];
  __builtin_amdgcn_sched_barrier(0);

  auto body = [&](const float4* t, int j0) {
#pragma unroll
    for (int u = 0; u < 4; ++u) {
      float d2 = __builtin_fmaf(mex, t[u].x,
                 __builtin_fmaf(mey, t[u].y,
                 __builtin_fmaf(mez, t[u].z, mew + t[u].w)));
      int slot = cnt < NS ? cnt : (NS - 1);
      lists[slot * 256 + tid] = (u16)(j0 + u);
      cnt += (d2 <= CUT2) ? 1 : 0;
    }
  };

  for (int g = 0; g < 64; g += 2) {
    const int j1 = jbase + (((g + 1) & 63) << 2);
#pragma unroll
    for (int u = 0; u < 4; ++u) tb[u] = mp[j1 + u];   // prefetch g+1
    __builtin_amdgcn_sched_barrier(0);
    body(ta, jbase + (g << 2));                        // process g
    const int j2 = jbase + (((g + 2) & 63) << 2);
#pragma unroll
    for (int u = 0; u < 4; ++u) ta[u] = mp[j2 + u];   // prefetch g+2 (wraps)
    __builtin_amdgcn_sched_barrier(0);
    body(tb, jbase + ((g + 1) << 2));                  // process g+1
  }
  if (cnt > NS) cnt = NS;

  // ---- phase 2: keys + bitonic sort 16 (12 real + 4 pads) ----
  const u32 PADK = 0x7F800000u | (u32)mloc;   // +inf self-pad, sorts last
  u32 r[32];
#pragma unroll
  for (int k = 0; k < 16; ++k) {
    u32 key = PADK;
    if (k < cnt) {
      int j = lists[k * 256 + tid];
      float4 cj = s4[j];                       // one ds_read_b128 gather
      float d2 = fmaxf(__builtin_fmaf(mex, cj.x,
                  __builtin_fmaf(mey, cj.y,
                  __builtin_fmaf(mez, cj.z, mew + cj.w))), 0.f);
      key = (__float_as_uint(d2) & KEYMASK) | (u32)j;
    }
    r[k] = key;
  }
  bitonic_pass<16, 2, 1>(r);
  bitonic_pass<16, 4, 2>(r); bitonic_pass<16, 4, 1>(r);
  bitonic_pass<16, 8, 4>(r); bitonic_pass<16, 8, 2>(r); bitonic_pass<16, 8, 1>(r);
  bitonic_pass<16,16, 8>(r); bitonic_pass<16,16, 4>(r); bitonic_pass<16,16, 2>(r); bitonic_pass<16,16, 1>(r);

  // ---- phase 3a: symmetric pair merge (q0<->q1, q2<->q3), 16 keys ----
  __syncthreads();                       // lists dead; alias lmem as publish buf
  {
    u32* myp = lmem + quarter * 1024 + ctr * 16;
#pragma unroll
    for (int k = 0; k < 16; ++k) myp[(k + ctr) & 15] = r[k];   // bank-swizzled
  }
  __syncthreads();
  {
    u32* op = lmem + (quarter ^ 1) * 1024 + ctr * 16;
#pragma unroll
    for (int i = 0; i < 16; ++i) r[16 + i] = op[((15 - i) + ctr) & 15]; // desc
  }
  // asc16 ++ desc16 = bitonic -> sorted pair-32
  bitonic_pass<32,32,16>(r); bitonic_pass<32,32, 8>(r); bitonic_pass<32,32, 4>(r);
  bitonic_pass<32,32, 2>(r); bitonic_pass<32,32, 1>(r);

  // ---- phase 3b: cross-pair merge. q0 publishes pairA-32, q2 pairB-32 ----
  __syncthreads();
  const int pairId = quarter >> 1;
  if ((quarter & 1) == 0) {
    u32* pp = lmem + pairId * 2048 + ctr * 32;
#pragma unroll
    for (int k = 0; k < 32; ++k) pp[(k + ctr) & 31] = r[k];
  }
  __syncthreads();
  {
    u32* opp = lmem + (1 - pairId) * 2048 + ctr * 32;
#pragma unroll
    for (int t = 0; t < 32; ++t) {
      u32 v = opp[((31 - t) + ctr) & 31];            // other pair, descending
      r[t] = r[t] < v ? r[t] : v;                    // lower half of bitonic-64
    }
  }
  // lower-32 is bitonic and holds the 32 smallest -> 5 passes sort it
  bitonic_pass<32,32,16>(r); bitonic_pass<32,32, 8>(r); bitonic_pass<32,32, 4>(r);
  bitonic_pass<32,32, 2>(r); bitonic_pass<32,32, 1>(r);

  // ---- phase 4: emit, one role per wave (all r[] indices compile-time) ----
  const long long E = (long long)NB * NM * NK;
  const float base = (float)((c >> 10) * NM);
  const float nmex = -mex, nmey = -mey, nmez = -mez;

  if (quarter == 0) {                    // src + dst
    vf4* ps = (vf4*)(out       + (size_t)c * NK);
    vf4* pd = (vf4*)(out +   E + (size_t)c * NK);
    const float fc = (float)c;
    const vf4 dstv = {fc, fc, fc, fc};
#pragma unroll
    for (int q = 0; q < 8; ++q) {
      float sv[4];
#pragma unroll
      for (int u = 0; u < 4; ++u) sv[u] = base + (float)(int)(r[4*q + u] & 1023u);
      ps[q] = (vf4){sv[0], sv[1], sv[2], sv[3]};
      pd[q] = dstv;
    }
  } else if (quarter == 1) {             // weights
    vf4* pw = (vf4*)(out + 2*E + (size_t)c * NK);
#pragma unroll
    for (int q = 0; q < 8; ++q) {
      float wv[4];
#pragma unroll
      for (int u = 0; u < 4; ++u) {
        u32 key = r[4*q + u];
        int idx = (int)(key & 1023u);
        float4 cj = s4[idx];
        bool valid = (key & KEYMASK) <= CUT2_BITS;   // pads (+inf) fail
        float vx = __builtin_fmaf(-0.5f, cj.x, nmex);
        float vy = __builtin_fmaf(-0.5f, cj.y, nmey);
        float vz = __builtin_fmaf(-0.5f, cj.z, nmez);
        bool wm  = valid && (idx != mloc);
        float d2s = vx*vx + vy*vy + vz*vz;
        wv[u] = wm ? sqrtf(d2s) : 0.0f;
      }
      pw[q] = (vf4){wv[0], wv[1], wv[2], wv[3]};
    }
  } else if (quarter == 2) {             // edge vectors 0..15
    vf4* pv = (vf4*)(out + 3*E + (size_t)c * NK * 3);
#pragma unroll
    for (int q = 0; q < 4; ++q) {
      float vv[12];
#pragma unroll
      for (int u = 0; u < 4; ++u) {
        int idx = (int)(r[4*q + u] & 1023u);
        float4 cj = s4[idx];
        vv[3*u+0] = __builtin_fmaf(-0.5f, cj.x, nmex);
        vv[3*u+1] = __builtin_fmaf(-0.5f, cj.y, nmey);
        vv[3*u+2] = __builtin_fmaf(-0.5f, cj.z, nmez);
      }
      pv[3*q+0] = (vf4){vv[0], vv[1], vv[2],  vv[3]};
      pv[3*q+1] = (vf4){vv[4], vv[5], vv[6],  vv[7]};
      pv[3*q+2] = (vf4){vv[8], vv[9], vv[10], vv[11]};
    }
  } else {                               // edge vectors 16..31
    vf4* pv = (vf4*)(out + 3*E + (size_t)c * NK * 3) + 12;
#pragma unroll
    for (int q = 0; q < 4; ++q) {
      float vv[12];
#pragma unroll
      for (int u = 0; u < 4; ++u) {
        int idx = (int)(r[16 + 4*q + u] & 1023u);
        float4 cj = s4[idx];
        vv[3*u+0] = __builtin_fmaf(-0.5f, cj.x, nmex);
        vv[3*u+1] = __builtin_fmaf(-0.5f, cj.y, nmey);
        vv[3*u+2] = __builtin_fmaf(-0.5f, cj.z, nmez);
      }
      pv[3*q+0] = (vf4){vv[0], vv[1], vv[2],  vv[3]};
      pv[3*q+1] = (vf4){vv[4], vv[5], vv[6],  vv[7]};
      pv[3*q+2] = (vf4){vv[8], vv[9], vv[10], vv[11]};
    }
  }
}

extern "C" void kernel_launch(void* const* d_in, const int* in_sizes, int n_in,
                              void* d_out, int out_size, void* d_ws, size_t ws_size,
                              hipStream_t stream) {
  const float* pos = (const float*)d_in[0];
  float* out = (float*)d_out;
  float4* scanb = (float4*)d_ws;                       // 2 MB
  hipLaunchKernelGGL(pack_atoms, dim3((NB*NM)/256), dim3(256), 0, stream, pos, scanb);
  hipLaunchKernelGGL(radius_knn, dim3(NB * (NM / 64)), dim3(256), 0, stream,
                     scanb, out);   // 2048 blocks: 128 mol x 16 center-groups
}